// Round 15
// baseline (292.010 us; speedup 1.0000x reference)
//
#include <hip/hip_runtime.h>
#include <hip/hip_bf16.h>
#include <hip/hip_fp16.h>
#include <math.h>

#define NEG_SLOPE 0.2f

typedef __attribute__((ext_vector_type(8))) short short8v;
typedef __attribute__((ext_vector_type(4))) float f32x4;

__device__ __forceinline__ float uas(unsigned int u) { return __uint_as_float(u); }

__device__ __forceinline__ unsigned short f2bf(float x) {
    __hip_bfloat16 b = __float2bfloat16(x);
    return *(unsigned short*)&b;
}

#define NPB_SHIFT 8
#define BCAP_SHIFT 13             // 8192 slots per bucket (mean 2558, +110 sigma)
#define BCAP (1 << BCAP_SHIFT)
#define BIN_EDGES 2048            // edges per scatter slice
#define BS_EPT    4               // 2048 / 512 threads (binscatter)
#define GEMM_BLOCKS 512           // persistent blocks (2 per CU)

// ---------------- W prep: extended bf16 fragment image -----------------------
__global__ void k_prep(const float* __restrict__ W, const float* __restrict__ al,
                       const float* __restrict__ ar, short* __restrict__ wfrag,
                       int* __restrict__ bcur, int NB) {
    int p = blockIdx.x * 256 + threadIdx.x;   // n*32+kg, 0..4607
    if (p < NB) bcur[p] = p << BCAP_SHIFT;
    if (p >= 144 * 32) return;
    int n = p >> 5, kg = p & 31;
    float v[8];
    if (n < 128) {
        const float* wp = W + (size_t)n * 256 + kg * 8;
        float4 v0 = *(const float4*)wp;
        float4 v1 = *(const float4*)(wp + 4);
        v[0] = v0.x; v[1] = v0.y; v[2] = v0.z; v[3] = v0.w;
        v[4] = v1.x; v[5] = v1.y; v[6] = v1.z; v[7] = v1.w;
    } else if (n < 136) {
        int i = n - 128, hh = i & 3, lr = i >> 2;
        const float* av = lr ? ar : al;
#pragma unroll
        for (int j = 0; j < 8; j++) v[j] = 0.f;
        for (int c = 0; c < 32; c++) {
            float a = av[hh * 32 + c];
            const float* wp = W + (size_t)(hh * 32 + c) * 256 + kg * 8;
#pragma unroll
            for (int j = 0; j < 8; j++) v[j] += a * wp[j];
        }
    } else {
#pragma unroll
        for (int j = 0; j < 8; j++) v[j] = 0.f;
    }
    short s8[8];
#pragma unroll
    for (int j = 0; j < 8; j++) s8[j] = (short)f2bf(v[j]);
    int kstep = kg >> 2, ntile = n >> 4;
    int L     = (kg & 3) * 16 + (n & 15);
    int slot  = kstep * 9 + ntile;
    *(short8v*)&wfrag[(slot * 64 + L) * 8] = *(short8v*)s8;
}

// ---------------- MFMA GEMM + fused el/er (unchanged from r14) ---------------
__global__ __launch_bounds__(512, 4) void k_gemm(const float* __restrict__ feat,
                                                 const short* __restrict__ wfrag,
                                                 unsigned short* __restrict__ hb,
                                                 float* __restrict__ el,
                                                 float* __restrict__ er, int N,
                                                 int ntiles) {
    __shared__ short wlds[36864];   // 72 KB: all 72 slots, linear
    const int t    = threadIdx.x;
    const int lane = t & 63;
    const int wave = t >> 6;        // 0..7
    const int g    = lane >> 4;     // k-quad
    const int c    = lane & 15;

#pragma unroll
    for (int i = 0; i < 9; i++) {
        int p = t + i * 512;                    // chunk 0..4607
        *(short8v*)&wlds[(size_t)p * 8] = *(const short8v*)&wfrag[(size_t)p * 8];
    }
    __syncthreads();

    for (int tile = blockIdx.x; tile < ntiles; tile += gridDim.x) {
        const int n0  = tile * 128;
        const int row = n0 + wave * 16 + c;
        const int rc  = row < N ? row : N - 1;
        const float* ap = feat + (size_t)rc * 256 + g * 8;

        float4 a4[16];
#pragma unroll
        for (int ks = 0; ks < 8; ks++) {
            a4[2 * ks]     = *(const float4*)(ap + ks * 32);
            a4[2 * ks + 1] = *(const float4*)(ap + ks * 32 + 4);
        }
#pragma unroll
        for (int i = 0; i < 16; i++)
            asm volatile("" :: "v"(a4[i].x), "v"(a4[i].y),
                              "v"(a4[i].z), "v"(a4[i].w));

        f32x4 acc[9];
#pragma unroll
        for (int nt = 0; nt < 9; nt++) acc[nt] = (f32x4){0.f, 0.f, 0.f, 0.f};

#pragma unroll
        for (int ks = 0; ks < 8; ks++) {
            float4 v0 = a4[2 * ks], v1 = a4[2 * ks + 1];
            short s8[8];
            s8[0] = (short)f2bf(v0.x); s8[1] = (short)f2bf(v0.y);
            s8[2] = (short)f2bf(v0.z); s8[3] = (short)f2bf(v0.w);
            s8[4] = (short)f2bf(v1.x); s8[5] = (short)f2bf(v1.y);
            s8[6] = (short)f2bf(v1.z); s8[7] = (short)f2bf(v1.w);
            short8v afrag = *(short8v*)s8;
#pragma unroll
            for (int nt = 0; nt < 9; nt++) {
                short8v b = *(short8v*)&wlds[(((size_t)ks * 9 + nt) * 64 + lane) * 8];
                acc[nt] = __builtin_amdgcn_mfma_f32_16x16x32_bf16(afrag, b, acc[nt], 0, 0, 0);
            }
        }

#pragma unroll
        for (int r = 0; r < 4; r++) {
            int m = n0 + wave * 16 + g * 4 + r;
            if (m < N) {
#pragma unroll
                for (int nt = 0; nt < 8; nt++)
                    hb[(size_t)m * 128 + nt * 16 + c] = f2bf(acc[nt][r]);
                float av = acc[8][r];
                if (c < 4)      el[(size_t)m * 4 + c]       = av;
                else if (c < 8) er[(size_t)m * 4 + (c - 4)] = av;
            }
        }
    }
}

// ---------------- binscatter (unchanged) -------------------------------------
__global__ __launch_bounds__(512) void k_binscatter(const int* __restrict__ src,
                                                    const int* __restrict__ dst,
                                                    int* __restrict__ bcur,
                                                    unsigned int* __restrict__ binned,
                                                    int E, int NB) {
    __shared__ int hist[512];
    __shared__ int scn[512];
    __shared__ int lcur[512];
    __shared__ int gdelta[512];
    __shared__ int ebuf[BIN_EDGES];   // 8 KB: src per local slot
    __shared__ int dbuf[BIN_EDGES];   // 8 KB: dst per local slot
    int t = threadIdx.x;
    hist[t] = 0;
    __syncthreads();
    int wbase = blockIdx.x * BIN_EDGES;
    int base  = wbase + t;
    int ne    = E - wbase; if (ne > BIN_EDGES) ne = BIN_EDGES;
    int sv[BS_EPT], dv[BS_EPT];
#pragma unroll
    for (int k = 0; k < BS_EPT; k++) {
        int idx = base + k * 512;
        if (idx < E) {
            sv[k] = src[idx];
            dv[k] = dst[idx];
            atomicAdd(&hist[dv[k] >> NPB_SHIFT], 1);
        } else {
            dv[k] = -1;
        }
    }
    __syncthreads();
    scn[t] = hist[t];
    __syncthreads();
    for (int off = 1; off < 512; off <<= 1) {
        int v = (t >= off) ? scn[t - off] : 0;
        __syncthreads();
        scn[t] += v;
        __syncthreads();
    }
    if (t < NB) {
        int h  = hist[t];
        int lb = scn[t] - h;
        int g  = h ? atomicAdd(&bcur[t], h) : 0;
        gdelta[t] = g - lb;
        lcur[t]   = lb;
    }
    __syncthreads();
#pragma unroll
    for (int k = 0; k < BS_EPT; k++) {
        if (dv[k] >= 0) {
            int bkt  = dv[k] >> NPB_SHIFT;
            int slot = atomicAdd(&lcur[bkt], 1);
            ebuf[slot] = sv[k];
            dbuf[slot] = dv[k];
        }
    }
    __syncthreads();
    for (int j = t; j < ne; j += 512) {
        int d = dbuf[j];
        binned[j + gdelta[d >> NPB_SHIFT]] =
            (unsigned int)ebuf[j] | ((unsigned int)(d & 255) << 24);
    }
}

// ---------------- CSR build + per-edge-head weight precompute ----------------
// One WG per bucket.  In the linear write-out pass each edge additionally
// computes w[h] = exp(leaky(el[src][h] + er[node][h])) ONCE (agg previously
// recomputed it 16x per edge across lanes), stores 4x bf16 to aw (8 B/edge,
// position-aligned with src_csr), and accumulates denom[node][h] via LDS
// float atomics -> written to global denom4.
__global__ __launch_bounds__(512) void k_csr(const unsigned int* __restrict__ binned,
                                             const int* __restrict__ bcur,
                                             const float* __restrict__ el,
                                             const float* __restrict__ er,
                                             int* __restrict__ startA,
                                             int* __restrict__ deg,
                                             int* __restrict__ src_csr,
                                             unsigned short* __restrict__ aw,
                                             float* __restrict__ denom4, int N) {
    __shared__ int hist[256];
    __shared__ int scn[256];
    __shared__ int cur[256];
    __shared__ int sbuf[4096];            // 16 KB staging
    __shared__ unsigned char nbuf[4096];  // 4 KB local-node per slot
    __shared__ float dsum[256][4];        // 4 KB denominators
    int b = blockIdx.x;
    int t = threadIdx.x;
    int base = b << BCAP_SHIFT;
    int cnt  = bcur[b] - base;
    int node0 = b << NPB_SHIFT;
    if (t < 256) hist[t] = 0;
    for (int i = t; i < 1024; i += 512) ((float*)dsum)[i] = 0.f;
    __syncthreads();
    for (int i = t; i < cnt; i += 512) {
        unsigned int e = binned[base + i];
        atomicAdd(&hist[e >> 24], 1);
    }
    __syncthreads();
    int h = (t < 256) ? hist[t] : 0;
    if (t < 256) scn[t] = h;
    __syncthreads();
    for (int off = 1; off < 256; off <<= 1) {
        int v = (t < 256 && t >= off) ? scn[t - off] : 0;
        __syncthreads();
        if (t < 256) scn[t] += v;
        __syncthreads();
    }
    if (t < 256) {
        int excl  = scn[t] - h;
        int gnode = node0 + t;
        if (gnode < N) { startA[gnode] = base + excl; deg[gnode] = h; }
        cur[t] = excl;
    }
    __syncthreads();
    if (cnt <= 4096) {
        for (int i = t; i < cnt; i += 512) {
            unsigned int e = binned[base + i];
            int ld = e >> 24;
            int p  = atomicAdd(&cur[ld], 1);
            sbuf[p] = (int)(e & 0xFFFFFFu);
            nbuf[p] = (unsigned char)ld;
        }
        __syncthreads();
        for (int i = t; i < cnt; i += 512) {
            int s  = sbuf[i];
            int ld = nbuf[i];
            src_csr[base + i] = s;
            float4 elv = *(const float4*)&el[(unsigned)s * 4];
            float4 erv = *(const float4*)&er[(unsigned)(node0 + ld) * 4];
            float w0 = elv.x + erv.x; w0 = fmaxf(w0, NEG_SLOPE * w0); w0 = __expf(w0);
            float w1 = elv.y + erv.y; w1 = fmaxf(w1, NEG_SLOPE * w1); w1 = __expf(w1);
            float w2 = elv.z + erv.z; w2 = fmaxf(w2, NEG_SLOPE * w2); w2 = __expf(w2);
            float w3 = elv.w + erv.w; w3 = fmaxf(w3, NEG_SLOPE * w3); w3 = __expf(w3);
            atomicAdd(&dsum[ld][0], w0);
            atomicAdd(&dsum[ld][1], w1);
            atomicAdd(&dsum[ld][2], w2);
            atomicAdd(&dsum[ld][3], w3);
            unsigned int lo = (unsigned int)f2bf(w0) | ((unsigned int)f2bf(w1) << 16);
            unsigned int hi = (unsigned int)f2bf(w2) | ((unsigned int)f2bf(w3) << 16);
            *(uint2*)&aw[(size_t)(base + i) * 4] = make_uint2(lo, hi);
        }
    } else {
        // fallback: direct scatter (degenerate distributions only)
        for (int i = t; i < cnt; i += 512) {
            unsigned int e = binned[base + i];
            int ld = e >> 24;
            int s  = (int)(e & 0xFFFFFFu);
            int p  = atomicAdd(&cur[ld], 1);
            src_csr[base + p] = s;
            float4 elv = *(const float4*)&el[(unsigned)s * 4];
            float4 erv = *(const float4*)&er[(unsigned)(node0 + ld) * 4];
            float w0 = elv.x + erv.x; w0 = fmaxf(w0, NEG_SLOPE * w0); w0 = __expf(w0);
            float w1 = elv.y + erv.y; w1 = fmaxf(w1, NEG_SLOPE * w1); w1 = __expf(w1);
            float w2 = elv.z + erv.z; w2 = fmaxf(w2, NEG_SLOPE * w2); w2 = __expf(w2);
            float w3 = elv.w + erv.w; w3 = fmaxf(w3, NEG_SLOPE * w3); w3 = __expf(w3);
            atomicAdd(&dsum[ld][0], w0);
            atomicAdd(&dsum[ld][1], w1);
            atomicAdd(&dsum[ld][2], w2);
            atomicAdd(&dsum[ld][3], w3);
            unsigned int lo = (unsigned int)f2bf(w0) | ((unsigned int)f2bf(w1) << 16);
            unsigned int hi = (unsigned int)f2bf(w2) | ((unsigned int)f2bf(w3) << 16);
            *(uint2*)&aw[(size_t)(base + p) * 4] = make_uint2(lo, hi);
        }
    }
    __syncthreads();
    if (t < 256) {
        int gnode = node0 + t;
        if (gnode < N)
            *(float4*)&denom4[(unsigned)gnode * 4] =
                make_float4(dsum[t][0], dsum[t][1], dsum[t][2], dsum[t][3]);
    }
}

// ---------------- gather-side aggregation: one wave per dst node -------------
// v4: weights precomputed per (edge, head) in k_csr -- the inner loop is now
// {src load, hbu gather, 2-B weight broadcast load, unpack, 4 fma, 2 add}:
// no exp/leaky/el-gather (16x redundant across lanes before), no dd accum.
__global__ __launch_bounds__(256) void k_agg(
        const unsigned int* __restrict__ hbu,
        const unsigned short* __restrict__ aw,
        const int* __restrict__ src_csr, const int* __restrict__ start,
        const int* __restrict__ deg, const float* __restrict__ denom4,
        const float* __restrict__ bias, float* __restrict__ out, int N) {
    int wid  = blockIdx.x * 4 + (threadIdx.x >> 6);
    int lane = threadIdx.x & 63;
    if (wid >= N) return;
    int beg = __builtin_amdgcn_readfirstlane(start[wid]);
    int dg  = __builtin_amdgcn_readfirstlane(deg[wid]);
    int head = lane >> 4;   // elements (2*lane, 2*lane+1) share one head

    float dden = denom4[(unsigned)(wid << 2) + head];
    float inv  = dden > 0.f ? 1.f / dden : 0.f;
    unsigned int uh = hbu[(unsigned)(wid << 6) + lane];  // own row, issued early
    float2 bv = ((const float2*)bias)[lane];

    float S1x = 0.f, S1y = 0.f, S2x = 0.f, S2y = 0.f;
    int i = 0;
    for (; i + 8 <= dg; i += 8) {
        int b = beg + i;
        int s[8];
#pragma unroll
        for (int k = 0; k < 8; k++) s[k] = src_csr[b + k];
        unsigned int u[8];
#pragma unroll
        for (int k = 0; k < 8; k++) u[k] = hbu[(unsigned)(s[k] << 6) + lane];
        unsigned short wv[8];
#pragma unroll
        for (int k = 0; k < 8; k++) wv[k] = aw[(unsigned)((b + k) << 2) + head];
#pragma unroll
        for (int k = 0; k < 8; k++) {
            float w = uas((unsigned int)wv[k] << 16);
            float x = uas(u[k] << 16), y = uas(u[k] & 0xFFFF0000u);
            S1x += x; S1y += y;
            S2x += w * x; S2y += w * y;
        }
    }
    for (; i + 4 <= dg; i += 4) {
        int b = beg + i;
        int s[4];
#pragma unroll
        for (int k = 0; k < 4; k++) s[k] = src_csr[b + k];
        unsigned int u[4];
#pragma unroll
        for (int k = 0; k < 4; k++) u[k] = hbu[(unsigned)(s[k] << 6) + lane];
        unsigned short wv[4];
#pragma unroll
        for (int k = 0; k < 4; k++) wv[k] = aw[(unsigned)((b + k) << 2) + head];
#pragma unroll
        for (int k = 0; k < 4; k++) {
            float w = uas((unsigned int)wv[k] << 16);
            float x = uas(u[k] << 16), y = uas(u[k] & 0xFFFF0000u);
            S1x += x; S1y += y;
            S2x += w * x; S2y += w * y;
        }
    }
    for (; i < dg; i++) {
        int b = beg + i;
        int s0 = src_csr[b];
        unsigned int u0 = hbu[(unsigned)(s0 << 6) + lane];
        float w0 = uas((unsigned int)aw[(unsigned)(b << 2) + head] << 16);
        float x0 = uas(u0 << 16), y0 = uas(u0 & 0xFFFF0000u);
        S1x += x0; S1y += y0;
        S2x += w0 * x0; S2y += w0 * y0;
    }

    float hvx = uas(uh << 16), hvy = uas(uh & 0xFFFF0000u);
    float ox = bv.x + hvx * S1x + S2x * inv;
    float oy = bv.y + hvy * S1y + S2y * inv;
    float2 o = {ox, oy};
    ((float2*)(out + (size_t)wid * 128))[lane] = o;
}

extern "C" void kernel_launch(void* const* d_in, const int* in_sizes, int n_in,
                              void* d_out, int out_size, void* d_ws, size_t ws_size,
                              hipStream_t stream) {
    const float* feat = (const float*)d_in[0];
    const float* W_fc = (const float*)d_in[1];
    const float* al   = (const float*)d_in[2];
    const float* ar   = (const float*)d_in[3];
    const float* bias = (const float*)d_in[4];
    const int*   src  = (const int*)d_in[5];
    const int*   dst  = (const int*)d_in[6];
    const int N = in_sizes[0] / 256;
    const int E = in_sizes[5];
    const int NB = (N + 255) >> NPB_SHIFT;   // <= 512 for N <= 131072

    char* ws = (char*)d_ws;
    size_t off = 0;
    unsigned int* hbu = (unsigned int*)(ws + off); off += (size_t)N * 64 * 4; // 25.6 MB
    float* el         = (float*)(ws + off); off += (size_t)N * 4 * 4;         // 1.6 MB
    float* er         = (float*)(ws + off); off += (size_t)N * 4 * 4;         // 1.6 MB
    int* startA       = (int*)(ws + off);   off += (size_t)N * 4;
    int* deg          = (int*)(ws + off);   off += (size_t)N * 4;
    float* denom4     = (float*)(ws + off); off += (size_t)N * 4 * 4;         // 1.6 MB
    int* src_csr      = (int*)(ws + off);   off += (size_t)NB * BCAP * 4;     // 12.8 MB
    unsigned int* binned = (unsigned int*)(ws + off); off += (size_t)NB * BCAP * 4; // 12.8 MB
    unsigned short* aw = (unsigned short*)(ws + off); off += (size_t)NB * BCAP * 8; // 25.6 MB
    short* wfrag      = (short*)(ws + off); off += (size_t)72 * 64 * 8 * 2;   // 72 KB
    int* bcur         = (int*)(ws + off);   off += 2048;

    float* out = (float*)d_out;

    int ntiles = (N + 127) / 128;
    int binWG  = (E + BIN_EDGES - 1) / BIN_EDGES;

    k_prep<<<18, 256, 0, stream>>>(W_fc, al, ar, wfrag, bcur, NB);
    k_gemm<<<GEMM_BLOCKS, 512, 0, stream>>>(feat, wfrag, (unsigned short*)hbu,
                                            el, er, N, ntiles);
    k_binscatter<<<binWG, 512, 0, stream>>>(src, dst, bcur, binned, E, NB);
    k_csr<<<NB, 512, 0, stream>>>(binned, bcur, el, er, startA, deg, src_csr,
                                  aw, denom4, N);
    k_agg<<<(N + 3) / 4, 256, 0, stream>>>(hbu, aw, src_csr, startA, deg,
                                           denom4, bias, out, N);
}

// Round 16
// 256.179 us; speedup vs baseline: 1.1399x; 1.1399x over previous
//
#include <hip/hip_runtime.h>
#include <hip/hip_bf16.h>
#include <hip/hip_fp16.h>
#include <math.h>

#define NEG_SLOPE 0.2f

typedef __attribute__((ext_vector_type(8))) short short8v;
typedef __attribute__((ext_vector_type(4))) float f32x4;

__device__ __forceinline__ float uas(unsigned int u) { return __uint_as_float(u); }

__device__ __forceinline__ unsigned short f2bf(float x) {
    __hip_bfloat16 b = __float2bfloat16(x);
    return *(unsigned short*)&b;
}

#define NPB_SHIFT 8
#define BCAP_SHIFT 13             // 8192 slots per bucket (mean 2558, +110 sigma)
#define BCAP (1 << BCAP_SHIFT)
#define BIN_EDGES 2048            // edges per scatter slice
#define BS_EPT    4               // 2048 / 512 threads (binscatter)

// ---------------- W prep: extended bf16 fragment image -----------------------
__global__ void k_prep(const float* __restrict__ W, const float* __restrict__ al,
                       const float* __restrict__ ar, short* __restrict__ wfrag,
                       int* __restrict__ bcur, int NB) {
    int p = blockIdx.x * 256 + threadIdx.x;   // n*32+kg, 0..4607
    if (p < NB) bcur[p] = p << BCAP_SHIFT;
    if (p >= 144 * 32) return;
    int n = p >> 5, kg = p & 31;
    float v[8];
    if (n < 128) {
        const float* wp = W + (size_t)n * 256 + kg * 8;
        float4 v0 = *(const float4*)wp;
        float4 v1 = *(const float4*)(wp + 4);
        v[0] = v0.x; v[1] = v0.y; v[2] = v0.z; v[3] = v0.w;
        v[4] = v1.x; v[5] = v1.y; v[6] = v1.z; v[7] = v1.w;
    } else if (n < 136) {
        int i = n - 128, hh = i & 3, lr = i >> 2;
        const float* av = lr ? ar : al;
#pragma unroll
        for (int j = 0; j < 8; j++) v[j] = 0.f;
        for (int c = 0; c < 32; c++) {
            float a = av[hh * 32 + c];
            const float* wp = W + (size_t)(hh * 32 + c) * 256 + kg * 8;
#pragma unroll
            for (int j = 0; j < 8; j++) v[j] += a * wp[j];
        }
    } else {
#pragma unroll
        for (int j = 0; j < 8; j++) v[j] = 0.f;
    }
    short s8[8];
#pragma unroll
    for (int j = 0; j < 8; j++) s8[j] = (short)f2bf(v[j]);
    int kstep = kg >> 2, ntile = n >> 4;
    int L     = (kg & 3) * 16 + (n & 15);
    int slot  = kstep * 9 + ntile;
    *(short8v*)&wfrag[(slot * 64 + L) * 8] = *(short8v*)s8;
}

// ---------------- MFMA GEMM + fused el/er ------------------------------------
// v7: COALESCED A-loads.  Old pattern: one load instruction touched 16 rows
// x 4 offsets = 64 distinct 64-B lines (a 64-transaction gather) -- explains
// 1.37 TB/s + all-pipes-idle across r5-r14.  Now each wave loads ONE feat row
// per pass (lane L -> bytes L*16..L*16+15: ONE transaction/instruction),
// converts to bf16, stages into a 32 KB LDS A-buffer with XOR swizzle
// (byte ^= (row&7)<<4; read would otherwise be same-bank across c-lanes).
// Tile = 64 rows; waves 0-3 compute ntiles 0-3, waves 4-7 ntiles 4-8 (same
// rows, disjoint outputs).  LDS 72+32 = 104 KB -> 1 block/CU, 256 blocks.
__global__ __launch_bounds__(512) void k_gemm(const float* __restrict__ feat,
                                              const short* __restrict__ wfrag,
                                              unsigned short* __restrict__ hb,
                                              float* __restrict__ el,
                                              float* __restrict__ er, int N,
                                              int ntiles) {
    __shared__ short wlds[36864];   // 72 KB: B image, all 72 slots linear
    __shared__ short alds[16384];   // 32 KB: A tile, 64 rows x 512 B (bf16)
    const int t    = threadIdx.x;
    const int lane = t & 63;
    const int wave = t >> 6;        // 0..7
    const int g    = lane >> 4;     // k-quad
    const int c    = lane & 15;
    const int rg   = wave & 3;      // row-group (16 rows)
    const bool hiW = wave >= 4;     // handles ntiles 4..8

    // ---- stage B once (4608 chunks of 16 B, linear 1:1)
#pragma unroll
    for (int i = 0; i < 9; i++) {
        int p = t + i * 512;
        *(short8v*)&wlds[(size_t)p * 8] = *(const short8v*)&wfrag[(size_t)p * 8];
    }
    __syncthreads();

    char* abase = (char*)alds;

    for (int tile = blockIdx.x; tile < ntiles; tile += gridDim.x) {
        const int n0 = tile * 64;

        // ---- stage A: 8 passes; each wave loads ONE row (1 KB contiguous)
#pragma unroll
        for (int p = 0; p < 8; p++) {
            int rowl = p * 8 + wave;
            int rc   = (n0 + rowl) < N ? (n0 + rowl) : N - 1;
            float4 v = *(const float4*)(feat + (size_t)rc * 256 + lane * 4);
            unsigned int lo = (unsigned int)f2bf(v.x) | ((unsigned int)f2bf(v.y) << 16);
            unsigned int hi = (unsigned int)f2bf(v.z) | ((unsigned int)f2bf(v.w) << 16);
            int byte = rowl * 512 + lane * 8;
            byte ^= (rowl & 7) << 4;
            *(uint2*)(abase + byte) = make_uint2(lo, hi);
        }
        __syncthreads();

        // ---- compute: per ks, 1 A ds_read + 4/5 B ds_reads + MFMA
        const int rowl = rg * 16 + c;
        const int aswz = (rowl & 7) << 4;
        if (!hiW) {
            f32x4 acc[4];
#pragma unroll
            for (int j = 0; j < 4; j++) acc[j] = (f32x4){0.f, 0.f, 0.f, 0.f};
#pragma unroll
            for (int ks = 0; ks < 8; ks++) {
                int abyte = (rowl * 512 + ks * 64 + g * 16) ^ aswz;
                short8v afrag = *(short8v*)(abase + abyte);
#pragma unroll
                for (int j = 0; j < 4; j++) {
                    short8v b = *(short8v*)&wlds[(((size_t)ks * 9 + j) * 64 + lane) * 8];
                    acc[j] = __builtin_amdgcn_mfma_f32_16x16x32_bf16(afrag, b, acc[j], 0, 0, 0);
                }
            }
            __syncthreads();   // A consumed; next staging may overwrite
#pragma unroll
            for (int r = 0; r < 4; r++) {
                int m = n0 + rg * 16 + g * 4 + r;
                if (m < N) {
#pragma unroll
                    for (int j = 0; j < 4; j++)
                        hb[(size_t)m * 128 + j * 16 + c] = f2bf(acc[j][r]);
                }
            }
        } else {
            f32x4 acc[5];
#pragma unroll
            for (int j = 0; j < 5; j++) acc[j] = (f32x4){0.f, 0.f, 0.f, 0.f};
#pragma unroll
            for (int ks = 0; ks < 8; ks++) {
                int abyte = (rowl * 512 + ks * 64 + g * 16) ^ aswz;
                short8v afrag = *(short8v*)(abase + abyte);
#pragma unroll
                for (int j = 0; j < 5; j++) {
                    short8v b = *(short8v*)&wlds[(((size_t)ks * 9 + 4 + j) * 64 + lane) * 8];
                    acc[j] = __builtin_amdgcn_mfma_f32_16x16x32_bf16(afrag, b, acc[j], 0, 0, 0);
                }
            }
            __syncthreads();
#pragma unroll
            for (int r = 0; r < 4; r++) {
                int m = n0 + rg * 16 + g * 4 + r;
                if (m < N) {
#pragma unroll
                    for (int j = 0; j < 4; j++)
                        hb[(size_t)m * 128 + (4 + j) * 16 + c] = f2bf(acc[j][r]);
                    float av = acc[4][r];
                    if (c < 4)      el[(size_t)m * 4 + c]       = av;
                    else if (c < 8) er[(size_t)m * 4 + (c - 4)] = av;
                }
            }
        }
    }
}

// ---------------- binscatter (r10, unchanged) --------------------------------
__global__ __launch_bounds__(512) void k_binscatter(const int* __restrict__ src,
                                                    const int* __restrict__ dst,
                                                    int* __restrict__ bcur,
                                                    unsigned int* __restrict__ binned,
                                                    int E, int NB) {
    __shared__ int hist[512];
    __shared__ int scn[512];
    __shared__ int lcur[512];
    __shared__ int gdelta[512];
    __shared__ int ebuf[BIN_EDGES];
    __shared__ int dbuf[BIN_EDGES];
    int t = threadIdx.x;
    hist[t] = 0;
    __syncthreads();
    int wbase = blockIdx.x * BIN_EDGES;
    int base  = wbase + t;
    int ne    = E - wbase; if (ne > BIN_EDGES) ne = BIN_EDGES;
    int sv[BS_EPT], dv[BS_EPT];
#pragma unroll
    for (int k = 0; k < BS_EPT; k++) {
        int idx = base + k * 512;
        if (idx < E) {
            sv[k] = src[idx];
            dv[k] = dst[idx];
            atomicAdd(&hist[dv[k] >> NPB_SHIFT], 1);
        } else {
            dv[k] = -1;
        }
    }
    __syncthreads();
    scn[t] = hist[t];
    __syncthreads();
    for (int off = 1; off < 512; off <<= 1) {
        int v = (t >= off) ? scn[t - off] : 0;
        __syncthreads();
        scn[t] += v;
        __syncthreads();
    }
    if (t < NB) {
        int h  = hist[t];
        int lb = scn[t] - h;
        int g  = h ? atomicAdd(&bcur[t], h) : 0;
        gdelta[t] = g - lb;
        lcur[t]   = lb;
    }
    __syncthreads();
#pragma unroll
    for (int k = 0; k < BS_EPT; k++) {
        if (dv[k] >= 0) {
            int bkt  = dv[k] >> NPB_SHIFT;
            int slot = atomicAdd(&lcur[bkt], 1);
            ebuf[slot] = sv[k];
            dbuf[slot] = dv[k];
        }
    }
    __syncthreads();
    for (int j = t; j < ne; j += 512) {
        int d = dbuf[j];
        binned[j + gdelta[d >> NPB_SHIFT]] =
            (unsigned int)ebuf[j] | ((unsigned int)(d & 255) << 24);
    }
}

// ---------------- CSR build (r10, unchanged) ---------------------------------
__global__ __launch_bounds__(512) void k_csr(const unsigned int* __restrict__ binned,
                                             const int* __restrict__ bcur,
                                             int* __restrict__ startA,
                                             int* __restrict__ deg,
                                             int* __restrict__ src_csr, int N) {
    __shared__ int hist[256];
    __shared__ int scn[256];
    __shared__ int cur[256];
    __shared__ int sbuf[4096];
    int b = blockIdx.x;
    int t = threadIdx.x;
    int base = b << BCAP_SHIFT;
    int cnt  = bcur[b] - base;
    int node0 = b << NPB_SHIFT;
    if (t < 256) hist[t] = 0;
    __syncthreads();
    for (int i = t; i < cnt; i += 512) {
        unsigned int e = binned[base + i];
        atomicAdd(&hist[e >> 24], 1);
    }
    __syncthreads();
    int h = (t < 256) ? hist[t] : 0;
    if (t < 256) scn[t] = h;
    __syncthreads();
    for (int off = 1; off < 256; off <<= 1) {
        int v = (t < 256 && t >= off) ? scn[t - off] : 0;
        __syncthreads();
        if (t < 256) scn[t] += v;
        __syncthreads();
    }
    if (t < 256) {
        int excl  = scn[t] - h;
        int gnode = node0 + t;
        if (gnode < N) { startA[gnode] = base + excl; deg[gnode] = h; }
        cur[t] = excl;
    }
    __syncthreads();
    if (cnt <= 4096) {
        for (int i = t; i < cnt; i += 512) {
            unsigned int e = binned[base + i];
            int p = atomicAdd(&cur[e >> 24], 1);
            sbuf[p] = (int)(e & 0xFFFFFFu);
        }
        __syncthreads();
        for (int i = t; i < cnt; i += 512)
            src_csr[base + i] = sbuf[i];
    } else {
        for (int i = t; i < cnt; i += 512) {
            unsigned int e = binned[base + i];
            int p = atomicAdd(&cur[e >> 24], 1);
            src_csr[base + p] = (int)(e & 0xFFFFFFu);
        }
    }
}

// ---------------- gather-side aggregation (r10, unchanged) -------------------
__global__ __launch_bounds__(256) void k_agg(
        const unsigned int* __restrict__ hbu,
        const float* __restrict__ el, const float* __restrict__ er,
        const int* __restrict__ src_csr, const int* __restrict__ start,
        const int* __restrict__ deg,
        const float* __restrict__ bias, float* __restrict__ out, int N) {
    int wid  = blockIdx.x * 4 + (threadIdx.x >> 6);
    int lane = threadIdx.x & 63;
    if (wid >= N) return;
    int beg = __builtin_amdgcn_readfirstlane(start[wid]);
    int dg  = __builtin_amdgcn_readfirstlane(deg[wid]);
    int head = lane >> 4;

    float er_own = er[(size_t)wid * 4 + head];
    unsigned int uh = hbu[(size_t)wid * 64 + lane];
    float2 bv = ((const float2*)bias)[lane];

    float S1x = 0.f, S1y = 0.f, S2x = 0.f, S2y = 0.f, dd = 0.f;
    int i = 0;
    for (; i + 8 <= dg; i += 8) {
        int b = beg + i;
        int s[8];
#pragma unroll
        for (int k = 0; k < 8; k++) s[k] = src_csr[b + k];
        unsigned int u[8];
#pragma unroll
        for (int k = 0; k < 8; k++) u[k] = hbu[(size_t)s[k] * 64 + lane];
        float ev[8];
#pragma unroll
        for (int k = 0; k < 8; k++) ev[k] = el[(size_t)s[k] * 4 + head];
#pragma unroll
        for (int k = 0; k < 8; k++) {
            float tt = ev[k] + er_own;
            tt = fmaxf(tt, NEG_SLOPE * tt);
            float w = __expf(tt);
            float x = uas(u[k] << 16), y = uas(u[k] & 0xFFFF0000u);
            S1x += x; S1y += y;
            S2x += w * x; S2y += w * y;
            dd  += w;
        }
    }
    for (; i + 4 <= dg; i += 4) {
        int b = beg + i;
        int s[4];
#pragma unroll
        for (int k = 0; k < 4; k++) s[k] = src_csr[b + k];
        unsigned int u[4];
#pragma unroll
        for (int k = 0; k < 4; k++) u[k] = hbu[(size_t)s[k] * 64 + lane];
        float ev[4];
#pragma unroll
        for (int k = 0; k < 4; k++) ev[k] = el[(size_t)s[k] * 4 + head];
#pragma unroll
        for (int k = 0; k < 4; k++) {
            float tt = ev[k] + er_own;
            tt = fmaxf(tt, NEG_SLOPE * tt);
            float w = __expf(tt);
            float x = uas(u[k] << 16), y = uas(u[k] & 0xFFFF0000u);
            S1x += x; S1y += y;
            S2x += w * x; S2y += w * y;
            dd  += w;
        }
    }
    for (; i < dg; i++) {
        int s0 = src_csr[beg + i];
        unsigned int u0 = hbu[(size_t)s0 * 64 + lane];
        float tt = el[(size_t)s0 * 4 + head] + er_own;
        tt = fmaxf(tt, NEG_SLOPE * tt);
        float w0 = __expf(tt);
        float x0 = uas(u0 << 16), y0 = uas(u0 & 0xFFFF0000u);
        S1x += x0; S1y += y0;
        S2x += w0 * x0; S2y += w0 * y0;
        dd  += w0;
    }

    float hvx = uas(uh << 16), hvy = uas(uh & 0xFFFF0000u);
    float inv = dd > 0.f ? 1.f / dd : 0.f;
    float ox = bv.x + hvx * S1x + S2x * inv;
    float oy = bv.y + hvy * S1y + S2y * inv;
    float2 o = {ox, oy};
    ((float2*)(out + (size_t)wid * 128))[lane] = o;
}

extern "C" void kernel_launch(void* const* d_in, const int* in_sizes, int n_in,
                              void* d_out, int out_size, void* d_ws, size_t ws_size,
                              hipStream_t stream) {
    const float* feat = (const float*)d_in[0];
    const float* W_fc = (const float*)d_in[1];
    const float* al   = (const float*)d_in[2];
    const float* ar   = (const float*)d_in[3];
    const float* bias = (const float*)d_in[4];
    const int*   src  = (const int*)d_in[5];
    const int*   dst  = (const int*)d_in[6];
    const int N = in_sizes[0] / 256;
    const int E = in_sizes[5];
    const int NB = (N + 255) >> NPB_SHIFT;   // <= 512 for N <= 131072

    char* ws = (char*)d_ws;
    size_t off = 0;
    unsigned int* hbu = (unsigned int*)(ws + off); off += (size_t)N * 64 * 4; // 25.6 MB
    float* el         = (float*)(ws + off); off += (size_t)N * 4 * 4;         // 1.6 MB
    float* er         = (float*)(ws + off); off += (size_t)N * 4 * 4;         // 1.6 MB
    int* startA       = (int*)(ws + off);   off += (size_t)N * 4;
    int* deg          = (int*)(ws + off);   off += (size_t)N * 4;
    int* src_csr      = (int*)(ws + off);   off += (size_t)NB * BCAP * 4;     // 12.8 MB
    unsigned int* binned = (unsigned int*)(ws + off); off += (size_t)NB * BCAP * 4; // 12.8 MB
    short* wfrag      = (short*)(ws + off); off += (size_t)72 * 64 * 8 * 2;   // 72 KB
    int* bcur         = (int*)(ws + off);   off += 2048;

    float* out = (float*)d_out;

    int ntiles = (N + 63) / 64;
    int binWG  = (E + BIN_EDGES - 1) / BIN_EDGES;

    k_prep<<<18, 256, 0, stream>>>(W_fc, al, ar, wfrag, bcur, NB);
    k_gemm<<<256, 512, 0, stream>>>(feat, wfrag, (unsigned short*)hbu,
                                    el, er, N, ntiles);
    k_binscatter<<<binWG, 512, 0, stream>>>(src, dst, bcur, binned, E, NB);
    k_csr<<<NB, 512, 0, stream>>>(binned, bcur, startA, deg, src_csr, N);
    k_agg<<<(N + 3) / 4, 256, 0, stream>>>(hbu, el, er, src_csr, startA, deg,
                                           bias, out, N);
}